// Round 9
// baseline (164.640 us; speedup 1.0000x reference)
//
#include <hip/hip_runtime.h>
#include <hip/hip_bf16.h>

// N=32 time, 32x32 grid, C=64 (H=4 x D=16), 3x3x3 offsets (M=27), 2 layers.
// R20 = 64-col waves. Accounting: R11-R19 all stream ~550MB/layer of K/V
// weights from L2 (2048 waves x 27m x 10KB private) ~= 16us at L2 BW — the
// invariant behind the ~40us layer. Each wave now computes 2 cells x 32 t
// (two 32-col B-sets) per weight load: traffic and load-issue per output
// halve. Block = 4 waves (hp x cellpair), halo 612 rows = 76.5KB LDS,
// grid (8,32) = 256 blocks = 1 block/CU = 1 wave/SIMD — occupancy proven
// irrelevant (R13); ILP comes from 2 independent per-set chains.
// __launch_bounds__(256,1): 512-VGPR budget, spill impossible-by-budget.
// Bias-in-K aug (R19) kept; no-max softmax in regs (R17) kept.

typedef short short8_t __attribute__((ext_vector_type(8)));
typedef float floatx16 __attribute__((ext_vector_type(16)));

__device__ __forceinline__ short f2bs(float f) {
    __hip_bfloat16 h = __float2bfloat16(f);
    return *reinterpret_cast<short*>(&h);
}
__device__ __forceinline__ float bs2f(short s) {
    union { unsigned u; float f; } v;
    v.u = ((unsigned)(unsigned short)s) << 16;
    return v.f;
}
// swizzled halo addressing: rowid in [0,612), 8 chunks of 8 shorts, pitch 64
__device__ __forceinline__ int hn_idx(int rowid, int chunk) {
    return rowid * 64 + ((chunk ^ (rowid & 7)) << 3);
}
// p(lane) + p(lane^32), all lanes (VALU pipe, no DS)
__device__ __forceinline__ float half_sum(float p) {
    float a = p, b = p;
    asm("v_permlane32_swap_b32 %0, %1" : "+v"(a), "+v"(b));
    return a + b;
}

// ---------------- prep: repack weights+bias-aug (coalesced) + BN sums ----------------
// blocks 0..109: one matrix each (incl. bias hi/lo aug chunk). 110..141: BN sums.
__global__ void prep_kernel(const float* __restrict__ Wq, const float* __restrict__ Wk,
                            const float* __restrict__ Wv, const float* __restrict__ bq,
                            const float* __restrict__ bk, const float* __restrict__ bv,
                            short* __restrict__ dst,
                            const float* __restrict__ x, float* __restrict__ sums) {
    if (blockIdx.x < 110) {
        __shared__ float Wf[4096];
        __shared__ float Bf[64];
        const int mat = blockIdx.x;
        const float *W, *B;
        if (mat < 2)       { W = Wq + mat * 4096;        B = bq + mat * 64; }
        else if (mat < 56) { W = Wk + (mat - 2) * 4096;  B = bk + (mat - 2) * 64; }
        else               { W = Wv + (mat - 56) * 4096; B = bv + (mat - 56) * 64; }
        const float4* W4 = (const float4*)W;
        #pragma unroll
        for (int i = 0; i < 4; ++i) {
            const int idx = threadIdx.x + i * 256;
            *(float4*)&Wf[idx * 4] = W4[idx];
        }
        if (threadIdx.x < 64) Bf[threadIdx.x] = B[threadIdx.x];
        __syncthreads();
        // entries: t2 = (hp*5+kk)*64 + lane, kk=4 is the bias aug chunk
        #pragma unroll
        for (int u = 0; u < 3; ++u) {
            const int t2 = u * 256 + threadIdx.x;
            if (t2 >= 640) break;
            const int hp = t2 / 320, rem = t2 - hp * 320;
            const int kk = rem >> 6, lane = rem & 63;
            short8_t v = {0, 0, 0, 0, 0, 0, 0, 0};
            if (kk < 4) {
                const int krow = kk * 16 + ((lane >> 5) << 3);
                const int col  = hp * 32 + (lane & 31);
                #pragma unroll
                for (int j = 0; j < 8; ++j) v[j] = f2bs(Wf[(krow + j) * 64 + col]);
            } else if ((lane >> 5) == 0) {
                const float b = Bf[hp * 32 + (lane & 31)];
                const short hi = f2bs(b);
                v[0] = hi;
                v[1] = f2bs(b - bs2f(hi));   // lo residual: hi+lo ~= b (f32)
            }
            *(short8_t*)&dst[(size_t)mat * 5120 + t2 * 8] = v;
        }
    } else {
        int bid = blockIdx.x - 110;
        int t = bid * 256 + threadIdx.x;          // 8192 threads x 3 float4
        const float4* x4 = (const float4*)x;
        float4 v0 = x4[t * 3 + 0], v1 = x4[t * 3 + 1], v2 = x4[t * 3 + 2];
        float vv[6];
        vv[0] = v0.x + v0.w + v1.z + v2.y;
        vv[1] = v0.y + v1.x + v1.w + v2.z;
        vv[2] = v0.z + v1.y + v2.x + v2.w;
        vv[3] = v0.x*v0.x + v0.w*v0.w + v1.z*v1.z + v2.y*v2.y;
        vv[4] = v0.y*v0.y + v1.x*v1.x + v1.w*v1.w + v2.z*v2.z;
        vv[5] = v0.z*v0.z + v1.y*v1.y + v2.x*v2.x + v2.w*v2.w;
        #pragma unroll
        for (int i = 0; i < 6; ++i) {
            #pragma unroll
            for (int off = 1; off < 64; off <<= 1) vv[i] += __shfl_xor(vv[i], off);
        }
        __shared__ float part[4][6];
        if ((threadIdx.x & 63) == 0) {
            #pragma unroll
            for (int i = 0; i < 6; ++i) part[threadIdx.x >> 6][i] = vv[i];
        }
        __syncthreads();
        if (threadIdx.x < 6)
            sums[bid * 8 + threadIdx.x] = part[0][threadIdx.x] + part[1][threadIdx.x] +
                                          part[2][threadIdx.x] + part[3][threadIdx.x];
    }
}

// ---------------- fused attention layer ----------------
// grid (bx=8, a=32); block 256 = 4 waves; wave = cp*2 + hp;
// hp = headpair (channels hp*32..+31); cp = cellpair (cells bb0+cp*2, +1).
// Wave covers its 2 cells x ALL 32 time rows = 64 cols as two 32-col B-sets
// (set ts: times ts*16..+15). lane: ci=(lane>>4)&1 cell, e=lane&15 time,
// h5=lane>>5. All 27 m's per wave; softmax in registers; no merge.
template <bool FIRST>
__global__ __launch_bounds__(256, 1)
void layer_fused(const float* __restrict__ x, const float* __restrict__ sums,
                 const float* __restrict__ W_in, const float* __restrict__ b_in,
                 const short* __restrict__ hbf_in, short* __restrict__ hbf_out,
                 const float* __restrict__ Wout, const float* __restrict__ bout,
                 float* __restrict__ out,
                 const short* __restrict__ wqB,
                 const short* __restrict__ wkB,
                 const short* __restrict__ wvB) {
    __shared__ short HnS[612 * 64];   // 76.5 KB halo; reused for hf (SECOND)
    __shared__ float Waux[256];
    __shared__ float bn6[6];

    const int tid = threadIdx.x;
    const int bb0 = blockIdx.x * 4, a = blockIdx.y;

    if (FIRST) {
        if (tid < 3) {
            float s = 0.f, qq = 0.f;
            #pragma unroll
            for (int p = 0; p < 32; ++p) { s += sums[p * 8 + tid]; qq += sums[p * 8 + 3 + tid]; }
            float mean = s * (1.f / 32768.f);
            float var  = qq * (1.f / 32768.f) - mean * mean;
            bn6[tid]     = mean;
            bn6[3 + tid] = rsqrtf(var + 1e-5f);
        }
        if (tid < 192) Waux[tid] = W_in[tid];
        else           Waux[tid] = b_in[tid - 192];
    } else {
        if (tid < 192)      Waux[tid] = Wout[tid];
        else if (tid < 195) Waux[tid] = bout[tid - 192];
    }
    __syncthreads();

    float mean0 = 0, mean1 = 0, mean2 = 0, rs0 = 0, rs1 = 0, rs2 = 0;
    if (FIRST) {
        mean0 = bn6[0]; mean1 = bn6[1]; mean2 = bn6[2];
        rs0 = bn6[3]; rs1 = bn6[4]; rs2 = bn6[5];
    }

    // ---- stage halo: 612 rows x 8 chunks of 8 bf16 ----
    // rowid = (spa*6 + jcol)*34 + r; r = time row (n = r-1 in [-1,32])
    for (int id = tid; id < 4896; id += 256) {
        int rowid = id >> 3, cc = id & 7;
        int rw = rowid / 34, r = rowid - rw * 34;
        int spa = rw / 6, jcol = rw - spa * 6;
        int aa = a + spa - 1, bb = bb0 + jcol - 1;
        int n  = r - 1;
        short8_t v = {0, 0, 0, 0, 0, 0, 0, 0};
        if ((unsigned)n < 32u && (unsigned)aa < 32u && (unsigned)bb < 32u) {
            int cell = (n * 32 + aa) * 32 + bb;
            if (FIRST) {
                float xn0 = (x[cell*3+0] - mean0) * rs0;
                float xn1 = (x[cell*3+1] - mean1) * rs1;
                float xn2 = (x[cell*3+2] - mean2) * rs2;
                #pragma unroll
                for (int j = 0; j < 8; ++j) {
                    int c = cc * 8 + j;
                    float h = Waux[192+c] + xn0*Waux[c] + xn1*Waux[64+c] + xn2*Waux[128+c];
                    v[j] = f2bs(h);
                }
            } else {
                v = *(const short8_t*)&hbf_in[cell * 64 + cc * 8];
            }
        }
        *(short8_t*)&HnS[hn_idx(rowid, cc)] = v;
    }
    __syncthreads();

    const int lane = tid & 63;
    const int wv4  = tid >> 6;
    const int hp   = wv4 & 1;        // headpair
    const int cp   = wv4 >> 1;       // cellpair
    const int e    = lane & 15;
    const int ci   = (lane >> 4) & 1;
    const int h5   = lane >> 5;
    const int cell4 = cp * 2 + ci;   // cell index within block, 0..3
    const int bcell = bb0 + cell4;   // absolute b of this lane's cell

    // validity masks
    unsigned amask = 0;
    #pragma unroll
    for (int d = 0; d < 3; ++d) if ((unsigned)(a + d - 1) < 32u) amask |= 1u << d;
    unsigned vmask = 0;
    #pragma unroll
    for (int j = 0; j < 3; ++j) if ((unsigned)(bcell + j - 1) < 32u) vmask |= 1u << j;

    const int eb = cell4 * 34 + e;   // per-lane halo-row offset (jcol=cell4 part)

    // constant aug B-operand: k-slot0=1, k-slot1=1 (hi+lo bias) for h5==0 lanes
    const short one_bf = (short)0x3F80;
    short8_t baug = {0, 0, 0, 0, 0, 0, 0, 0};
    if (h5 == 0) { baug[0] = one_bf; baug[1] = one_bf; }
    const floatx16 ZERO = {0,0,0,0, 0,0,0,0, 0,0,0,0, 0,0,0,0};

    // ---- Q projection: per set, aug + 4 MFMAs (center: di=1,dj=1,tk=1) ----
    floatx16 qv0, qv1;
    {
        const short8_t* wqp = (const short8_t*)&wqB[hp * 2560 + lane * 8];
#define Q_SET(QV, TS)                                                              \
        {                                                                          \
            const int hrow = 7 * 34 + eb + (TS) * 16 + 1;                          \
            const int hb = hrow * 64, xr = hrow & 7;                               \
            const short8_t b0 = *(const short8_t*)&HnS[hb + (((0 + h5) ^ xr) << 3)];\
            const short8_t b1 = *(const short8_t*)&HnS[hb + (((2 + h5) ^ xr) << 3)];\
            const short8_t b2 = *(const short8_t*)&HnS[hb + (((4 + h5) ^ xr) << 3)];\
            const short8_t b3 = *(const short8_t*)&HnS[hb + (((6 + h5) ^ xr) << 3)];\
            QV = __builtin_amdgcn_mfma_f32_32x32x16_bf16(wqp[256], baug, ZERO, 0, 0, 0);\
            QV = __builtin_amdgcn_mfma_f32_32x32x16_bf16(wqp[0],   b0, QV, 0, 0, 0);\
            QV = __builtin_amdgcn_mfma_f32_32x32x16_bf16(wqp[64],  b1, QV, 0, 0, 0);\
            QV = __builtin_amdgcn_mfma_f32_32x32x16_bf16(wqp[128], b2, QV, 0, 0, 0);\
            QV = __builtin_amdgcn_mfma_f32_32x32x16_bf16(wqp[192], b3, QV, 0, 0, 0);\
        }
        Q_SET(qv0, 0)
        Q_SET(qv1, 1)
#undef Q_SET
    }

    // ---- fused K/V pass: ALL 27 m's per wave, 2 column-sets per weight load ----
    floatx16 o0 = {0,0,0,0, 0,0,0,0, 0,0,0,0, 0,0,0,0};
    floatx16 o1 = {0,0,0,0, 0,0,0,0, 0,0,0,0, 0,0,0,0};
    float ssA0 = 0.f, ssB0 = 0.f, ssA1 = 0.f, ssB1 = 0.f;

    const short* wkBase = wkB + hp * 2560 + lane * 8;
    const short* wvBase = wvB + hp * 2560 + lane * 8;

#define KV_SET(HROWB, QV, O, SSA, SSB)                                             \
    {                                                                              \
        const int hrow_ = (HROWB);                                                 \
        const int hb_ = hrow_ * 64, xr_ = hrow_ & 7;                               \
        const short8_t b0_ = *(const short8_t*)&HnS[hb_ + (((0 + h5) ^ xr_) << 3)];\
        const short8_t b1_ = *(const short8_t*)&HnS[hb_ + (((2 + h5) ^ xr_) << 3)];\
        const short8_t b2_ = *(const short8_t*)&HnS[hb_ + (((4 + h5) ^ xr_) << 3)];\
        const short8_t b3_ = *(const short8_t*)&HnS[hb_ + (((6 + h5) ^ xr_) << 3)];\
        floatx16 kacc_ = __builtin_amdgcn_mfma_f32_32x32x16_bf16(wk4, baug, ZERO, 0, 0, 0);\
        kacc_ = __builtin_amdgcn_mfma_f32_32x32x16_bf16(wk0, b0_, kacc_, 0, 0, 0); \
        kacc_ = __builtin_amdgcn_mfma_f32_32x32x16_bf16(wk1, b1_, kacc_, 0, 0, 0); \
        kacc_ = __builtin_amdgcn_mfma_f32_32x32x16_bf16(wk2, b2_, kacc_, 0, 0, 0); \
        kacc_ = __builtin_amdgcn_mfma_f32_32x32x16_bf16(wk3, b3_, kacc_, 0, 0, 0); \
        floatx16 vacc_ = __builtin_amdgcn_mfma_f32_32x32x16_bf16(wv4, baug, ZERO, 0, 0, 0);\
        vacc_ = __builtin_amdgcn_mfma_f32_32x32x16_bf16(wv0, b0_, vacc_, 0, 0, 0); \
        vacc_ = __builtin_amdgcn_mfma_f32_32x32x16_bf16(wv1, b1_, vacc_, 0, 0, 0); \
        vacc_ = __builtin_amdgcn_mfma_f32_32x32x16_bf16(wv2, b2_, vacc_, 0, 0, 0); \
        vacc_ = __builtin_amdgcn_mfma_f32_32x32x16_bf16(wv3, b3_, vacc_, 0, 0, 0); \
        float pA0_ = kacc_[0] * QV[0] + kacc_[1] * QV[1];                          \
        float pA1_ = kacc_[2] * QV[2] + kacc_[3] * QV[3];                          \
        float pA2_ = kacc_[4] * QV[4] + kacc_[5] * QV[5];                          \
        float pA3_ = kacc_[6] * QV[6] + kacc_[7] * QV[7];                          \
        float pB0_ = kacc_[8] * QV[8] + kacc_[9] * QV[9];                          \
        float pB1_ = kacc_[10] * QV[10] + kacc_[11] * QV[11];                      \
        float pB2_ = kacc_[12] * QV[12] + kacc_[13] * QV[13];                      \
        float pB3_ = kacc_[14] * QV[14] + kacc_[15] * QV[15];                      \
        float pA_ = (pA0_ + pA1_) + (pA2_ + pA3_);                                 \
        float pB_ = (pB0_ + pB1_) + (pB2_ + pB3_);                                 \
        pA_ = half_sum(pA_);                                                       \
        pB_ = half_sum(pB_);                                                       \
        const float wA_ = __expf(pA_) * mf;                                        \
        const float wB_ = __expf(pB_) * mf;                                        \
        SSA += wA_; SSB += wB_;                                                    \
        _Pragma("unroll")                                                          \
        for (int r = 0; r < 8; ++r)  O[r] += wA_ * vacc_[r];                       \
        _Pragma("unroll")                                                          \
        for (int r = 8; r < 16; ++r) O[r] += wB_ * vacc_[r];                       \
    }

    for (int t = 0; t < 3; ++t) {
        const short* wkT = wkBase + t * 46080;   // 9 * 5120
        const short* wvT = wvBase + t * 46080;
        #pragma unroll
        for (int sp = 0; sp < 9; ++sp) {
            const int di = sp / 3, dj = sp - 3 * (sp / 3);
            const short8_t wk0 = *(const short8_t*)&wkT[sp * 5120 + 0];
            const short8_t wk1 = *(const short8_t*)&wkT[sp * 5120 + 512];
            const short8_t wk2 = *(const short8_t*)&wkT[sp * 5120 + 1024];
            const short8_t wk3 = *(const short8_t*)&wkT[sp * 5120 + 1536];
            const short8_t wk4 = *(const short8_t*)&wkT[sp * 5120 + 2048];
            const short8_t wv0 = *(const short8_t*)&wvT[sp * 5120 + 0];
            const short8_t wv1 = *(const short8_t*)&wvT[sp * 5120 + 512];
            const short8_t wv2 = *(const short8_t*)&wvT[sp * 5120 + 1024];
            const short8_t wv3 = *(const short8_t*)&wvT[sp * 5120 + 1536];
            const short8_t wv4 = *(const short8_t*)&wvT[sp * 5120 + 2048];
            const float mf = (float)(((amask >> di) & (vmask >> dj)) & 1u);
            const int hrowb = (di * 6 + dj) * 34 + t + eb;
            KV_SET(hrowb,      qv0, o0, ssA0, ssB0)
            KV_SET(hrowb + 16, qv1, o1, ssA1, ssB1)
        }
    }
#undef KV_SET

    // ---- normalize (complete softmax: this wave saw all 27 m's) ----
    {
        const float iA0 = 1.0f / ssA0, iB0 = 1.0f / ssB0;
        const float iA1 = 1.0f / ssA1, iB1 = 1.0f / ssB1;
        #pragma unroll
        for (int r = 0; r < 8; ++r)  { o0[r] *= iA0; o1[r] *= iA1; }
        #pragma unroll
        for (int r = 8; r < 16; ++r) { o0[r] *= iB0; o1[r] *= iB1; }
    }

    // ---- epilogue ----
    if (FIRST) {
#define EPI_FIRST(OV, TS)                                                          \
        {                                                                          \
            const int n_ = (TS) * 16 + e;                                          \
            const int cell_ = (n_ * 32 + a) * 32 + bcell;                          \
            const float xn0_ = (x[cell_*3+0] - mean0) * rs0;                       \
            const float xn1_ = (x[cell_*3+1] - mean1) * rs1;                       \
            const float xn2_ = (x[cell_*3+2] - mean2) * rs2;                       \
            _Pragma("unroll")                                                      \
            for (int g = 0; g < 4; ++g) {                                          \
                short4 hb4_; short* hbp_ = (short*)&hb4_;                          \
                _Pragma("unroll")                                                  \
                for (int i = 0; i < 4; ++i) {                                      \
                    const int c_ = hp * 32 + g * 8 + 4 * h5 + i;                   \
                    const float res_ = Waux[192+c_] + xn0_*Waux[c_] +              \
                                       xn1_*Waux[64+c_] + xn2_*Waux[128+c_];       \
                    hbp_[i] = f2bs(OV[g * 4 + i] + res_);                          \
                }                                                                  \
                *(short4*)&hbf_out[cell_ * 64 + hp * 32 + g * 8 + 4 * h5] = hb4_;  \
            }                                                                      \
        }
        EPI_FIRST(o0, 0)
        EPI_FIRST(o1, 1)
#undef EPI_FIRST
    } else {
        __syncthreads();                   // all halo reads done; reuse LDS for hf
        float* hf = (float*)HnS;           // [128 cols][pitch 68] = 34.8 KB
#define EPI_SECOND(OV, TS)                                                         \
        {                                                                          \
            const int n_ = (TS) * 16 + e;                                          \
            const int cell_ = (n_ * 32 + a) * 32 + bcell;                          \
            const int bcol_ = cell4 * 32 + n_;                                     \
            _Pragma("unroll")                                                      \
            for (int g = 0; g < 4; ++g) {                                          \
                const short4 hb4_ = *(const short4*)&hbf_in[cell_ * 64 + hp * 32 + g * 8 + 4 * h5];\
                float4 tv_ = make_float4(OV[g*4+0] + bs2f(hb4_.x),                 \
                                         OV[g*4+1] + bs2f(hb4_.y),                 \
                                         OV[g*4+2] + bs2f(hb4_.z),                 \
                                         OV[g*4+3] + bs2f(hb4_.w));                \
                *(float4*)&hf[bcol_ * 68 + hp * 32 + g * 8 + 4 * h5] = tv_;        \
            }                                                                      \
        }
        EPI_SECOND(o0, 0)
        EPI_SECOND(o1, 1)
#undef EPI_SECOND
        __syncthreads();
        // out-proj: 384 outputs (128 cols x 3 features), 64-ch dot each
        for (int oid = tid; oid < 384; oid += 256) {
            const int rowglob = oid / 3, f = oid - rowglob * 3;
            float acc = Waux[192 + f];
            #pragma unroll 8
            for (int cc = 0; cc < 64; ++cc) acc += hf[rowglob * 68 + cc] * Waux[cc * 3 + f];
            const int cellb = bb0 + (rowglob >> 5), n = rowglob & 31;
            out[((n * 32 + a) * 32 + cellb) * 3 + f] = acc;
        }
    }
}

extern "C" void kernel_launch(void* const* d_in, const int* in_sizes, int n_in,
                              void* d_out, int out_size, void* d_ws, size_t ws_size,
                              hipStream_t stream) {
    const float* x     = (const float*)d_in[0];
    const float* W_in  = (const float*)d_in[1];
    const float* b_in  = (const float*)d_in[2];
    const float* W_out = (const float*)d_in[3];
    const float* b_out = (const float*)d_in[4];
    const float* Wq    = (const float*)d_in[5];
    const float* bq    = (const float*)d_in[6];
    const float* Wk    = (const float*)d_in[7];
    const float* bk    = (const float*)d_in[8];
    const float* Wv    = (const float*)d_in[9];
    const float* bv    = (const float*)d_in[10];

    float* ws    = (float*)d_ws;
    float* sums  = ws;                          // 32 x 8 floats (BN partials)
    short* h1bf  = (short*)(ws + 256);          // 2M shorts (4 MB)
    short* wB    = h1bf + 2097152;              // 110 x 5120 bf16 (1.1 MB)
    float* out   = (float*)d_out;

    prep_kernel<<<142, 256, 0, stream>>>(Wq, Wk, Wv, bq, bk, bv, wB, x, sums);

    const short* wq0 = wB;                const short* wq1 = wB + 5120;
    const short* wk0 = wB + 2 * 5120;     const short* wk1 = wB + (2 + 27) * 5120;
    const short* wv0 = wB + 56 * 5120;    const short* wv1 = wB + (56 + 27) * 5120;

    dim3 grid(8, 32);
    layer_fused<true><<<grid, 256, 0, stream>>>(
        x, sums, W_in, b_in, nullptr, h1bf, nullptr, nullptr, nullptr,
        wq0, wk0, wv0);
    layer_fused<false><<<grid, 256, 0, stream>>>(
        nullptr, nullptr, nullptr, nullptr, h1bf, nullptr, W_out, b_out, out,
        wq1, wk1, wv1);
}

// Round 10
// 132.804 us; speedup vs baseline: 1.2397x; 1.2397x over previous
//
#include <hip/hip_runtime.h>
#include <hip/hip_bf16.h>

// N=32 time, 32x32 grid, C=64 (H=4 x D=16), 3x3x3 offsets (M=27), 2 layers.
// R21 = R19 (no-m-split, 27-m wave loop, bias-in-K aug, softmax in regs,
// 2 waves/SIMD) + depth-1 weight prefetch. R20's 1-wave/SIMD 64-col variant
// regressed (53us, spill at 256 VGPR): below 2 waves/SIMD the serial
// load->MFMA->dot->exp chain is fully exposed. R19 keeps 2 waves/SIMD; its
// one untested exposure is per-m weight-load latency (10 global loads
// consumed immediately). R15/R16 prefetch attempts failed on register
// budget (R16: 170-VGPR budget made the compiler discard the ping-pong).
// Under (256,2) = 256-VGPR budget the 20-reg ping-pong fits (~170 live).
// Tripwire: WRITE_SIZE >> 4MB = spill = revert.

typedef short short8_t __attribute__((ext_vector_type(8)));
typedef float floatx16 __attribute__((ext_vector_type(16)));

__device__ __forceinline__ short f2bs(float f) {
    __hip_bfloat16 h = __float2bfloat16(f);
    return *reinterpret_cast<short*>(&h);
}
__device__ __forceinline__ float bs2f(short s) {
    union { unsigned u; float f; } v;
    v.u = ((unsigned)(unsigned short)s) << 16;
    return v.f;
}
// swizzled halo addressing: rowid in [0,324), 8 chunks of 8 shorts, pitch 64
__device__ __forceinline__ int hn_idx(int rowid, int chunk) {
    return rowid * 64 + ((chunk ^ (rowid & 7)) << 3);
}
// p(lane) + p(lane^32), all lanes (VALU pipe, no DS)
__device__ __forceinline__ float half_sum(float p) {
    float a = p, b = p;
    asm("v_permlane32_swap_b32 %0, %1" : "+v"(a), "+v"(b));
    return a + b;
}

// ---------------- prep: repack weights+bias-aug (coalesced) + BN sums ----------------
// blocks 0..109: one matrix each (incl. bias hi/lo aug chunk). 110..141: BN sums.
__global__ void prep_kernel(const float* __restrict__ Wq, const float* __restrict__ Wk,
                            const float* __restrict__ Wv, const float* __restrict__ bq,
                            const float* __restrict__ bk, const float* __restrict__ bv,
                            short* __restrict__ dst,
                            const float* __restrict__ x, float* __restrict__ sums) {
    if (blockIdx.x < 110) {
        __shared__ float Wf[4096];
        __shared__ float Bf[64];
        const int mat = blockIdx.x;
        const float *W, *B;
        if (mat < 2)       { W = Wq + mat * 4096;        B = bq + mat * 64; }
        else if (mat < 56) { W = Wk + (mat - 2) * 4096;  B = bk + (mat - 2) * 64; }
        else               { W = Wv + (mat - 56) * 4096; B = bv + (mat - 56) * 64; }
        const float4* W4 = (const float4*)W;
        #pragma unroll
        for (int i = 0; i < 4; ++i) {
            const int idx = threadIdx.x + i * 256;
            *(float4*)&Wf[idx * 4] = W4[idx];
        }
        if (threadIdx.x < 64) Bf[threadIdx.x] = B[threadIdx.x];
        __syncthreads();
        // entries: t2 = (hp*5+kk)*64 + lane, kk=4 is the bias aug chunk
        #pragma unroll
        for (int u = 0; u < 3; ++u) {
            const int t2 = u * 256 + threadIdx.x;
            if (t2 >= 640) break;
            const int hp = t2 / 320, rem = t2 - hp * 320;
            const int kk = rem >> 6, lane = rem & 63;
            short8_t v = {0, 0, 0, 0, 0, 0, 0, 0};
            if (kk < 4) {
                const int krow = kk * 16 + ((lane >> 5) << 3);
                const int col  = hp * 32 + (lane & 31);
                #pragma unroll
                for (int j = 0; j < 8; ++j) v[j] = f2bs(Wf[(krow + j) * 64 + col]);
            } else if ((lane >> 5) == 0) {
                const float b = Bf[hp * 32 + (lane & 31)];
                const short hi = f2bs(b);
                v[0] = hi;
                v[1] = f2bs(b - bs2f(hi));   // lo residual: hi+lo ~= b (f32)
            }
            *(short8_t*)&dst[(size_t)mat * 5120 + t2 * 8] = v;
        }
    } else {
        int bid = blockIdx.x - 110;
        int t = bid * 256 + threadIdx.x;          // 8192 threads x 3 float4
        const float4* x4 = (const float4*)x;
        float4 v0 = x4[t * 3 + 0], v1 = x4[t * 3 + 1], v2 = x4[t * 3 + 2];
        float vv[6];
        vv[0] = v0.x + v0.w + v1.z + v2.y;
        vv[1] = v0.y + v1.x + v1.w + v2.z;
        vv[2] = v0.z + v1.y + v2.x + v2.w;
        vv[3] = v0.x*v0.x + v0.w*v0.w + v1.z*v1.z + v2.y*v2.y;
        vv[4] = v0.y*v0.y + v1.x*v1.x + v1.w*v1.w + v2.z*v2.z;
        vv[5] = v0.z*v0.z + v1.y*v1.y + v2.x*v2.x + v2.w*v2.w;
        #pragma unroll
        for (int i = 0; i < 6; ++i) {
            #pragma unroll
            for (int off = 1; off < 64; off <<= 1) vv[i] += __shfl_xor(vv[i], off);
        }
        __shared__ float part[4][6];
        if ((threadIdx.x & 63) == 0) {
            #pragma unroll
            for (int i = 0; i < 6; ++i) part[threadIdx.x >> 6][i] = vv[i];
        }
        __syncthreads();
        if (threadIdx.x < 6)
            sums[bid * 8 + threadIdx.x] = part[0][threadIdx.x] + part[1][threadIdx.x] +
                                          part[2][threadIdx.x] + part[3][threadIdx.x];
    }
}

// ---------------- fused attention layer ----------------
// grid (bx=8, a=32, nb=2); block 256 = 4 waves; wave = cg*2 + hp;
// hp = headpair (channels hp*32..+31); cg = colgroup (cells bb0+cg*2, +1).
// lane: col = lane&31 -> (ci = col>>4 cell-in-group, e = col&15 time row);
// h5 = lane>>5. Each wave: all 27 m's, softmax in registers, no merge.
template <bool FIRST>
__global__ __launch_bounds__(256, 2)
void layer_fused(const float* __restrict__ x, const float* __restrict__ sums,
                 const float* __restrict__ W_in, const float* __restrict__ b_in,
                 const short* __restrict__ hbf_in, short* __restrict__ hbf_out,
                 const float* __restrict__ Wout, const float* __restrict__ bout,
                 float* __restrict__ out,
                 const short* __restrict__ wqB,
                 const short* __restrict__ wkB,
                 const short* __restrict__ wvB) {
    __shared__ short HnS[324 * 64];   // 41.5 KB halo; reused for hf (SECOND)
    __shared__ float Waux[256];
    __shared__ float bn6[6];

    const int tid = threadIdx.x;
    const int bb0 = blockIdx.x * 4, a = blockIdx.y, nb = blockIdx.z;

    if (FIRST) {
        if (tid < 3) {
            float s = 0.f, qq = 0.f;
            #pragma unroll
            for (int p = 0; p < 32; ++p) { s += sums[p * 8 + tid]; qq += sums[p * 8 + 3 + tid]; }
            float mean = s * (1.f / 32768.f);
            float var  = qq * (1.f / 32768.f) - mean * mean;
            bn6[tid]     = mean;
            bn6[3 + tid] = rsqrtf(var + 1e-5f);
        }
        if (tid < 192) Waux[tid] = W_in[tid];
        else           Waux[tid] = b_in[tid - 192];
    } else {
        if (tid < 192)      Waux[tid] = Wout[tid];
        else if (tid < 195) Waux[tid] = bout[tid - 192];
    }
    __syncthreads();

    float mean0 = 0, mean1 = 0, mean2 = 0, rs0 = 0, rs1 = 0, rs2 = 0;
    if (FIRST) {
        mean0 = bn6[0]; mean1 = bn6[1]; mean2 = bn6[2];
        rs0 = bn6[3]; rs1 = bn6[4]; rs2 = bn6[5];
    }

    // ---- stage halo: 324 rows x 8 chunks of 8 bf16 ----
    // rowid = rw*18 + r; rw = spa*6 + jcol (3 spa x 6 jcol), r = time row
    for (int id = tid; id < 2592; id += 256) {
        int rowid = id >> 3, cc = id & 7;
        int r = rowid % 18;
        int rw = rowid / 18;
        int spa = rw / 6, jcol = rw - spa * 6;
        int aa = a + spa - 1, bb = bb0 + jcol - 1;
        int n  = nb * 16 + r - 1;
        short8_t v = {0, 0, 0, 0, 0, 0, 0, 0};
        if ((unsigned)n < 32u && (unsigned)aa < 32u && (unsigned)bb < 32u) {
            int cell = (n * 32 + aa) * 32 + bb;
            if (FIRST) {
                float xn0 = (x[cell*3+0] - mean0) * rs0;
                float xn1 = (x[cell*3+1] - mean1) * rs1;
                float xn2 = (x[cell*3+2] - mean2) * rs2;
                #pragma unroll
                for (int j = 0; j < 8; ++j) {
                    int c = cc * 8 + j;
                    float h = Waux[192+c] + xn0*Waux[c] + xn1*Waux[64+c] + xn2*Waux[128+c];
                    v[j] = f2bs(h);
                }
            } else {
                v = *(const short8_t*)&hbf_in[cell * 64 + cc * 8];
            }
        }
        *(short8_t*)&HnS[hn_idx(rowid, cc)] = v;
    }
    __syncthreads();

    const int lane = tid & 63;
    const int wv4  = tid >> 6;
    const int hp   = wv4 & 1;        // headpair
    const int cg   = wv4 >> 1;       // colgroup (2 cells)
    const int col  = lane & 31;
    const int e    = col & 15;
    const int ci   = col >> 4;
    const int h5   = lane >> 5;
    const int cell4 = cg * 2 + ci;   // cell index within block, 0..3
    const int bcell = bb0 + cell4;   // absolute b of this lane's cell

    // validity masks
    unsigned amask = 0;
    #pragma unroll
    for (int d = 0; d < 3; ++d) if ((unsigned)(a + d - 1) < 32u) amask |= 1u << d;
    unsigned vmask = 0;
    #pragma unroll
    for (int j = 0; j < 3; ++j) if ((unsigned)(bcell + j - 1) < 32u) vmask |= 1u << j;

    const int elane = cell4 * 18 + e;   // per-lane halo-row offset

    // constant aug B-operand: k-slot0=1, k-slot1=1 (hi+lo bias) for h5==0 lanes
    const short one_bf = (short)0x3F80;
    short8_t baug = {0, 0, 0, 0, 0, 0, 0, 0};
    if (h5 == 0) { baug[0] = one_bf; baug[1] = one_bf; }
    const floatx16 ZERO = {0,0,0,0, 0,0,0,0, 0,0,0,0, 0,0,0,0};

    // ---- Q projection (center: spa=1 -> rw = 7 + cell4): aug + 4 MFMAs ----
    floatx16 qv;
    {
        const int hrow = (7 + cell4) * 18 + e + 1;
        const int hb = hrow * 64, xr = hrow & 7;
        const short8_t b0 = *(const short8_t*)&HnS[hb + (((0 + h5) ^ xr) << 3)];
        const short8_t b1 = *(const short8_t*)&HnS[hb + (((2 + h5) ^ xr) << 3)];
        const short8_t b2 = *(const short8_t*)&HnS[hb + (((4 + h5) ^ xr) << 3)];
        const short8_t b3 = *(const short8_t*)&HnS[hb + (((6 + h5) ^ xr) << 3)];
        const short8_t* wqp = (const short8_t*)&wqB[hp * 2560 + lane * 8];
        qv = __builtin_amdgcn_mfma_f32_32x32x16_bf16(wqp[256], baug, ZERO, 0, 0, 0);
        qv = __builtin_amdgcn_mfma_f32_32x32x16_bf16(wqp[0],   b0, qv, 0, 0, 0);
        qv = __builtin_amdgcn_mfma_f32_32x32x16_bf16(wqp[64],  b1, qv, 0, 0, 0);
        qv = __builtin_amdgcn_mfma_f32_32x32x16_bf16(wqp[128], b2, qv, 0, 0, 0);
        qv = __builtin_amdgcn_mfma_f32_32x32x16_bf16(wqp[192], b3, qv, 0, 0, 0);
    }

    // ---- fused K/V pass: ALL 27 m's per wave, depth-1 weight prefetch ----
    floatx16 o = {0,0,0,0, 0,0,0,0, 0,0,0,0, 0,0,0,0};
    float ssA = 0.f, ssB = 0.f;

    const short* wkBase = wkB + hp * 2560 + lane * 8;
    const short* wvBase = wvB + hp * 2560 + lane * 8;

    short8_t kP0, kP1, kP2, kP3, kP4, vP0, vP1, vP2, vP3, vP4;
    short8_t kQ0, kQ1, kQ2, kQ3, kQ4, vQ0, vQ1, vQ2, vQ3, vQ4;
    kP0 = *(const short8_t*)&wkBase[0];
    kP1 = *(const short8_t*)&wkBase[512];
    kP2 = *(const short8_t*)&wkBase[1024];
    kP3 = *(const short8_t*)&wkBase[1536];
    kP4 = *(const short8_t*)&wkBase[2048];
    vP0 = *(const short8_t*)&wvBase[0];
    vP1 = *(const short8_t*)&wvBase[512];
    vP2 = *(const short8_t*)&wvBase[1024];
    vP3 = *(const short8_t*)&wvBase[1536];
    vP4 = *(const short8_t*)&wvBase[2048];

#define KV_BODY(CK0,CK1,CK2,CK3,CK4, CV0,CV1,CV2,CV3,CV4,                          \
                NK0,NK1,NK2,NK3,NK4, NV0,NV1,NV2,NV3,NV4, MV)                      \
    {                                                                              \
        const int m_  = (MV);                                                      \
        const int mn_ = (m_ + 1 < 27) ? m_ + 1 : m_;                               \
        /* prefetch next-m weights first: in flight across this whole body */      \
        NK0 = *(const short8_t*)&wkBase[mn_ * 5120 + 0];                           \
        NK1 = *(const short8_t*)&wkBase[mn_ * 5120 + 512];                         \
        NK2 = *(const short8_t*)&wkBase[mn_ * 5120 + 1024];                        \
        NK3 = *(const short8_t*)&wkBase[mn_ * 5120 + 1536];                        \
        NK4 = *(const short8_t*)&wkBase[mn_ * 5120 + 2048];                        \
        NV0 = *(const short8_t*)&wvBase[mn_ * 5120 + 0];                           \
        NV1 = *(const short8_t*)&wvBase[mn_ * 5120 + 512];                         \
        NV2 = *(const short8_t*)&wvBase[mn_ * 5120 + 1024];                        \
        NV3 = *(const short8_t*)&wvBase[mn_ * 5120 + 1536];                        \
        NV4 = *(const short8_t*)&wvBase[mn_ * 5120 + 2048];                        \
        const int t_  = (m_ * 57) >> 9;                                            \
        const int sp_ = m_ - 9 * t_;                                               \
        const int di_ = (sp_ * 11) >> 5;                                           \
        const int dj_ = sp_ - 3 * di_;                                             \
        const int hrow_ = di_ * 108 + dj_ * 18 + t_ + elane;                       \
        const int hb_ = hrow_ * 64, xr_ = hrow_ & 7;                               \
        const short8_t b0_ = *(const short8_t*)&HnS[hb_ + (((0 + h5) ^ xr_) << 3)];\
        const short8_t b1_ = *(const short8_t*)&HnS[hb_ + (((2 + h5) ^ xr_) << 3)];\
        const short8_t b2_ = *(const short8_t*)&HnS[hb_ + (((4 + h5) ^ xr_) << 3)];\
        const short8_t b3_ = *(const short8_t*)&HnS[hb_ + (((6 + h5) ^ xr_) << 3)];\
        floatx16 kacc_ = __builtin_amdgcn_mfma_f32_32x32x16_bf16(CK4, baug, ZERO, 0, 0, 0);\
        kacc_ = __builtin_amdgcn_mfma_f32_32x32x16_bf16(CK0, b0_, kacc_, 0, 0, 0); \
        kacc_ = __builtin_amdgcn_mfma_f32_32x32x16_bf16(CK1, b1_, kacc_, 0, 0, 0); \
        kacc_ = __builtin_amdgcn_mfma_f32_32x32x16_bf16(CK2, b2_, kacc_, 0, 0, 0); \
        kacc_ = __builtin_amdgcn_mfma_f32_32x32x16_bf16(CK3, b3_, kacc_, 0, 0, 0); \
        floatx16 vacc_ = __builtin_amdgcn_mfma_f32_32x32x16_bf16(CV4, baug, ZERO, 0, 0, 0);\
        vacc_ = __builtin_amdgcn_mfma_f32_32x32x16_bf16(CV0, b0_, vacc_, 0, 0, 0); \
        vacc_ = __builtin_amdgcn_mfma_f32_32x32x16_bf16(CV1, b1_, vacc_, 0, 0, 0); \
        vacc_ = __builtin_amdgcn_mfma_f32_32x32x16_bf16(CV2, b2_, vacc_, 0, 0, 0); \
        vacc_ = __builtin_amdgcn_mfma_f32_32x32x16_bf16(CV3, b3_, vacc_, 0, 0, 0); \
        float pA_ = kacc_[0] * qv[0];                                              \
        _Pragma("unroll")                                                          \
        for (int r = 1; r < 8; ++r) pA_ += kacc_[r] * qv[r];                       \
        float pB_ = kacc_[8] * qv[8];                                              \
        _Pragma("unroll")                                                          \
        for (int r = 9; r < 16; ++r) pB_ += kacc_[r] * qv[r];                      \
        pA_ = half_sum(pA_);                                                       \
        pB_ = half_sum(pB_);                                                       \
        const float mf_ = (float)(((amask >> di_) & (vmask >> dj_)) & 1u);         \
        const float wA_ = __expf(pA_) * mf_;                                       \
        const float wB_ = __expf(pB_) * mf_;                                       \
        ssA += wA_; ssB += wB_;                                                    \
        _Pragma("unroll")                                                          \
        for (int r = 0; r < 8; ++r)  o[r] += wA_ * vacc_[r];                       \
        _Pragma("unroll")                                                          \
        for (int r = 8; r < 16; ++r) o[r] += wB_ * vacc_[r];                       \
    }

    for (int m = 0; m < 27; m += 2) {
        KV_BODY(kP0,kP1,kP2,kP3,kP4, vP0,vP1,vP2,vP3,vP4,
                kQ0,kQ1,kQ2,kQ3,kQ4, vQ0,vQ1,vQ2,vQ3,vQ4, m)
        if (m + 1 < 27)
        KV_BODY(kQ0,kQ1,kQ2,kQ3,kQ4, vQ0,vQ1,vQ2,vQ3,vQ4,
                kP0,kP1,kP2,kP3,kP4, vP0,vP1,vP2,vP3,vP4, m + 1)
    }
#undef KV_BODY

    // ---- normalize (complete softmax: this wave saw all 27 m's) ----
    {
        const float invA = 1.0f / ssA;
        const float invB = 1.0f / ssB;
        #pragma unroll
        for (int r = 0; r < 8; ++r)  o[r] *= invA;
        #pragma unroll
        for (int r = 8; r < 16; ++r) o[r] *= invB;
    }

    // ---- epilogue ----
    const int n = nb * 16 + e;
    const int cell = (n * 32 + a) * 32 + bcell;
    if (FIRST) {
        const float xn0 = (x[cell*3+0] - mean0) * rs0;
        const float xn1 = (x[cell*3+1] - mean1) * rs1;
        const float xn2 = (x[cell*3+2] - mean2) * rs2;
        #pragma unroll
        for (int g = 0; g < 4; ++g) {
            short4 hb4; short* hbp = (short*)&hb4;
            #pragma unroll
            for (int i = 0; i < 4; ++i) {
                const int c = hp * 32 + g * 8 + 4 * h5 + i;
                const float res = Waux[192+c] + xn0*Waux[c] + xn1*Waux[64+c] + xn2*Waux[128+c];
                hbp[i] = f2bs(o[g * 4 + i] + res);
            }
            *(short4*)&hbf_out[cell * 64 + hp * 32 + g * 8 + 4 * h5] = hb4;
        }
    } else {
        __syncthreads();                   // all halo reads done; reuse LDS for hf
        float* hf = (float*)HnS;           // [64 cols][pitch 68]
        const int bcol = cell4 * 16 + e;   // 0..63
        #pragma unroll
        for (int g = 0; g < 4; ++g) {
            const short4 hb4 = *(const short4*)&hbf_in[cell * 64 + hp * 32 + g * 8 + 4 * h5];
            float4 tv = make_float4(o[g*4+0] + bs2f(hb4.x), o[g*4+1] + bs2f(hb4.y),
                                    o[g*4+2] + bs2f(hb4.z), o[g*4+3] + bs2f(hb4.w));
            *(float4*)&hf[bcol * 68 + hp * 32 + g * 8 + 4 * h5] = tv;
        }
        __syncthreads();
        // out-proj: 192 outputs (64 cols x 3 features), 64-ch dot each
        if (tid < 192) {
            const int rowglob = tid / 3, f = tid - rowglob * 3;  // rowglob = bcol
            float acc = Waux[192 + f];
            #pragma unroll 8
            for (int cc = 0; cc < 64; ++cc) acc += hf[rowglob * 68 + cc] * Waux[cc * 3 + f];
            const int cellb = bb0 + (rowglob >> 4), row = rowglob & 15;
            out[(((nb * 16 + row) * 32 + a) * 32 + cellb) * 3 + f] = acc;
        }
    }
}

extern "C" void kernel_launch(void* const* d_in, const int* in_sizes, int n_in,
                              void* d_out, int out_size, void* d_ws, size_t ws_size,
                              hipStream_t stream) {
    const float* x     = (const float*)d_in[0];
    const float* W_in  = (const float*)d_in[1];
    const float* b_in  = (const float*)d_in[2];
    const float* W_out = (const float*)d_in[3];
    const float* b_out = (const float*)d_in[4];
    const float* Wq    = (const float*)d_in[5];
    const float* bq    = (const float*)d_in[6];
    const float* Wk    = (const float*)d_in[7];
    const float* bk    = (const float*)d_in[8];
    const float* Wv    = (const float*)d_in[9];
    const float* bv    = (const float*)d_in[10];

    float* ws    = (float*)d_ws;
    float* sums  = ws;                          // 32 x 8 floats (BN partials)
    short* h1bf  = (short*)(ws + 256);          // 2M shorts (4 MB)
    short* wB    = h1bf + 2097152;              // 110 x 5120 bf16 (1.1 MB)
    float* out   = (float*)d_out;

    prep_kernel<<<142, 256, 0, stream>>>(Wq, Wk, Wv, bq, bk, bv, wB, x, sums);

    const short* wq0 = wB;                const short* wq1 = wB + 5120;
    const short* wk0 = wB + 2 * 5120;     const short* wk1 = wB + (2 + 27) * 5120;
    const short* wv0 = wB + 56 * 5120;    const short* wv1 = wB + (56 + 27) * 5120;

    dim3 grid(8, 32, 2);
    layer_fused<true><<<grid, 256, 0, stream>>>(
        x, sums, W_in, b_in, nullptr, h1bf, nullptr, nullptr, nullptr,
        wq0, wk0, wv0);
    layer_fused<false><<<grid, 256, 0, stream>>>(
        nullptr, nullptr, nullptr, nullptr, h1bf, nullptr, W_out, b_out, out,
        wq1, wk1, wv1);
}